// Round 1
// 1313.759 us; speedup vs baseline: 1.3198x; 1.3198x over previous
//
#include <hip/hip_runtime.h>
#include <math.h>

#define BB 256
#define TT 16
#define CC 40
#define HH 4
#define DD 10
#define VV 50257
#define ROWS (BB*TT)            // 4096
#define S_CHUNKS 8
#define CHUNK 6284              // ceil(VV/8) rounded up to multiple of 4; 8*6284=50272>=VV

// ---------------- Kernel 1: embeddings + attention -> out_rows[4096][40] ----
__global__ __launch_bounds__(64) void attn_kernel(
    const int* __restrict__ idx, const float* __restrict__ tok_emb,
    const float* __restrict__ pos_emb, const float* __restrict__ Wq,
    const float* __restrict__ Wk, const float* __restrict__ Wv,
    float* __restrict__ out_rows)
{
    __shared__ float xs[TT][CC];
    __shared__ float qs[HH][TT][DD], ks[HH][TT][DD], vs2[HH][TT][DD];
    const int b = blockIdx.x;
    const int tid = threadIdx.x;

    for (int i = tid; i < TT*CC; i += 64) {
        int t = i / CC, c = i % CC;
        int tok = idx[b*TT + t];
        xs[t][c] = tok_emb[tok*CC + c] + pos_emb[t*CC + c];   // pos = t % 16 = t
    }
    __syncthreads();

    const int h = tid >> 4, t = tid & 15;
    float qd[DD], kd[DD], vd[DD];
    #pragma unroll
    for (int d = 0; d < DD; ++d) { qd[d] = 0.f; kd[d] = 0.f; vd[d] = 0.f; }
    for (int c = 0; c < CC; ++c) {
        float xv = xs[t][c];
        int base = h*CC*DD + c*DD;
        #pragma unroll
        for (int d = 0; d < DD; ++d) {
            qd[d] += xv * Wq[base + d];
            kd[d] += xv * Wk[base + d];
            vd[d] += xv * Wv[base + d];
        }
    }
    #pragma unroll
    for (int d = 0; d < DD; ++d) { qs[h][t][d] = qd[d]; ks[h][t][d] = kd[d]; vs2[h][t][d] = vd[d]; }
    __syncthreads();

    // causal scores over s <= t, NO 1/sqrt(d) scaling (faithful to reference)
    float sc[TT];
    float m = -1e30f;
    for (int s = 0; s <= t; ++s) {
        float a = 0.f;
        #pragma unroll
        for (int d = 0; d < DD; ++d) a += qd[d] * ks[h][s][d];
        sc[s] = a;
        m = fmaxf(m, a);
    }
    float z = 0.f;
    for (int s = 0; s <= t; ++s) { sc[s] = __expf(sc[s] - m); z += sc[s]; }
    float inv = 1.0f / z;
    float od[DD];
    #pragma unroll
    for (int d = 0; d < DD; ++d) od[d] = 0.f;
    for (int s = 0; s <= t; ++s) {
        float p = sc[s] * inv;
        #pragma unroll
        for (int d = 0; d < DD; ++d) od[d] += p * vs2[h][s][d];
    }
    const int row = b*TT + t;
    #pragma unroll
    for (int d = 0; d < DD; ++d) out_rows[row*CC + h*DD + d] = od[d];
}

// ---------------- Kernel 2: logits + fused partial sum-exp ------------------
// grid = (ROWS/16) * S_CHUNKS blocks; block owns 16 rows x one V-chunk.
// Each thread owns 4 column streams (va, va+256, va+512, va+768): 64 FMAs per
// c-iteration from 4 L2 loads + 4 LDS broadcast reads. Logits tiny so sum-exp
// needs no max shift. Stores are nontemporal (write-once stream, 823 MB).
__global__ __launch_bounds__(256, 4) void logits_kernel(
    const float* __restrict__ out_rows, const float* __restrict__ lm_W,
    const float* __restrict__ lm_b, float* __restrict__ logits,
    float* __restrict__ partials)
{
    __shared__ float outT[CC][16];     // [c][r] transposed, rows of 16 floats (64B)
    __shared__ float red[16][4];
    const int sidx = blockIdx.x & (S_CHUNKS - 1);
    const int g    = blockIdx.x >> 3;
    const int tid  = threadIdx.x;
    const int r0   = g * 16;

    for (int i = tid; i < 16*CC; i += 256) {
        int r = i / CC, c = i % CC;
        outT[c][r] = out_rows[(r0 + r)*CC + c];
    }
    __syncthreads();

    const int vs = sidx * CHUNK;
    const int ve = min(VV, vs + CHUNK);

    float sumexp[16];
    #pragma unroll
    for (int r = 0; r < 16; ++r) sumexp[r] = 0.f;

    for (int va = vs + tid; va < ve; va += 1024) {
        const int v1 = va + 256, v2 = va + 512, v3 = va + 768;
        const bool h1 = (v1 < ve), h2 = (v2 < ve), h3 = (v3 < ve);
        const int a1 = h1 ? v1 : va;          // safe addresses when out of range
        const int a2 = h2 ? v2 : va;
        const int a3 = h3 ? v3 : va;

        float acc0[16], acc1[16], acc2[16], acc3[16];
        #pragma unroll
        for (int r = 0; r < 16; ++r) { acc0[r]=0.f; acc1[r]=0.f; acc2[r]=0.f; acc3[r]=0.f; }

        const float* wp = lm_W;
        #pragma unroll 4
        for (int c = 0; c < CC; ++c) {
            const float w0 = wp[va], w1 = wp[a1], w2 = wp[a2], w3 = wp[a3];
            const float4* xt = reinterpret_cast<const float4*>(&outT[c][0]);
            const float4 x0 = xt[0], x1 = xt[1], x2 = xt[2], x3 = xt[3];
            const float xv[16] = {x0.x,x0.y,x0.z,x0.w, x1.x,x1.y,x1.z,x1.w,
                                  x2.x,x2.y,x2.z,x2.w, x3.x,x3.y,x3.z,x3.w};
            #pragma unroll
            for (int r = 0; r < 16; ++r) {
                acc0[r] += xv[r]*w0;
                acc1[r] += xv[r]*w1;
                acc2[r] += xv[r]*w2;
                acc3[r] += xv[r]*w3;
            }
            wp += VV;
        }

        const float bias0 = lm_b[va];
        const float bias1 = lm_b[a1];
        const float bias2 = lm_b[a2];
        const float bias3 = lm_b[a3];
        #pragma unroll
        for (int r = 0; r < 16; ++r) {
            const size_t rowb = (size_t)(r0 + r) * VV;
            float l0 = acc0[r] + bias0;
            __builtin_nontemporal_store(l0, &logits[rowb + va]);
            float se = __expf(l0);
            if (h1) { float l1 = acc1[r] + bias1;
                      __builtin_nontemporal_store(l1, &logits[rowb + v1]);
                      se += __expf(l1); }
            if (h2) { float l2 = acc2[r] + bias2;
                      __builtin_nontemporal_store(l2, &logits[rowb + v2]);
                      se += __expf(l2); }
            if (h3) { float l3 = acc3[r] + bias3;
                      __builtin_nontemporal_store(l3, &logits[rowb + v3]);
                      se += __expf(l3); }
            sumexp[r] += se;
        }
    }

    // reduce per-row sum-exp across the 4 waves
    const int lane = tid & 63, wv = tid >> 6;
    #pragma unroll
    for (int r = 0; r < 16; ++r) {
        float sv = sumexp[r];
        for (int off = 32; off > 0; off >>= 1) sv += __shfl_down(sv, off);
        if (lane == 0) red[r][wv] = sv;
    }
    __syncthreads();
    if (tid < 16) {
        float zz = red[tid][0] + red[tid][1] + red[tid][2] + red[tid][3];
        partials[(r0 + tid)*S_CHUNKS + sidx] = zz;
    }
}

// ---------------- Kernel 3a: per-row loss, parallel over 16 blocks ----------
// Target logit is read directly from the logits array kernel 2 just stored —
// no lm_W gather recompute, no single-block serialization.
__global__ __launch_bounds__(256) void loss_partial_kernel(
    const int* __restrict__ targets, const float* __restrict__ logits,
    const float* __restrict__ partials, float* __restrict__ block_sums)
{
    __shared__ float red[256];
    const int tid = threadIdx.x;
    const int r = blockIdx.x * 256 + tid;      // 16 blocks * 256 = 4096 rows

    float z = 0.f;
    #pragma unroll
    for (int s = 0; s < S_CHUNKS; ++s) z += partials[r*S_CHUNKS + s];
    const int tgt = targets[r];
    const float lt = logits[(size_t)r*VV + tgt];
    red[tid] = logf(z) - lt;                   // -(logit_t - logsumexp)
    __syncthreads();
    for (int off = 128; off > 0; off >>= 1) {
        if (tid < off) red[tid] += red[tid + off];
        __syncthreads();
    }
    if (tid == 0) block_sums[blockIdx.x] = red[0];
}

// ---------------- Kernel 3b: final reduce ----------------------------------
__global__ __launch_bounds__(64) void loss_final_kernel(
    const float* __restrict__ block_sums, float* __restrict__ loss_out)
{
    const int tid = threadIdx.x;
    float v = (tid < 16) ? block_sums[tid] : 0.f;
    for (int off = 32; off > 0; off >>= 1) v += __shfl_down(v, off);
    if (tid == 0) loss_out[0] = v / (float)ROWS;
}

// ---------------- launch ---------------------------------------------------
extern "C" void kernel_launch(void* const* d_in, const int* in_sizes, int n_in,
                              void* d_out, int out_size, void* d_ws, size_t ws_size,
                              hipStream_t stream) {
    const int*   idx     = (const int*)d_in[0];
    const int*   targets = (const int*)d_in[1];
    const float* tok_emb = (const float*)d_in[2];
    const float* pos_emb = (const float*)d_in[3];
    const float* Wq      = (const float*)d_in[4];
    const float* Wk      = (const float*)d_in[5];
    const float* Wv      = (const float*)d_in[6];
    const float* lm_W    = (const float*)d_in[7];
    const float* lm_b    = (const float*)d_in[8];

    float* logits   = (float*)d_out;
    float* loss_out = logits + (size_t)ROWS * VV;   // last element of d_out
    float* out_rows = (float*)d_ws;                 // 4096*40 fp32
    float* partials = out_rows + ROWS*CC;           // 4096*8  fp32
    // block_sums reuses out_rows[0..15]: out_rows is dead after logits_kernel,
    // and loss_partial_kernel (the writer) runs strictly after it on the stream.
    float* block_sums = out_rows;

    attn_kernel<<<BB, 64, 0, stream>>>(idx, tok_emb, pos_emb, Wq, Wk, Wv, out_rows);
    logits_kernel<<<(ROWS/16)*S_CHUNKS, 256, 0, stream>>>(out_rows, lm_W, lm_b, logits, partials);
    loss_partial_kernel<<<16, 256, 0, stream>>>(targets, logits, partials, block_sums);
    loss_final_kernel<<<1, 64, 0, stream>>>(block_sums, loss_out);
}